// Round 7
// baseline (1528.693 us; speedup 1.0000x reference)
//
#include <hip/hip_runtime.h>
#include <cstdint>
#include <cstddef>

#define XLD 161   // x row stride = NFEAT + EXTRA + 1

typedef float f4u __attribute__((ext_vector_type(4), aligned(4)));  // unaligned-tolerant
typedef float f4a __attribute__((ext_vector_type(4)));              // 16B-aligned
typedef float f3u __attribute__((ext_vector_type(3), aligned(4)));

// ============================ CSR build ============================
__global__ void hist_kernel(const int* __restrict__ row, int* __restrict__ cnt, int E) {
    for (int e = blockIdx.x * blockDim.x + threadIdx.x; e < E; e += gridDim.x * blockDim.x)
        atomicAdd(&cnt[row[e]], 1);
}

__global__ __launch_bounds__(256)
void scan1_kernel(const int* __restrict__ cnt, int* __restrict__ offs,
                  int* __restrict__ bsums, int n) {
    int t = threadIdx.x;
    int gid = blockIdx.x * 256 + t;
    int v = (gid < n) ? cnt[gid] : 0;
    int x = v;
#pragma unroll
    for (int o = 1; o < 64; o <<= 1) { int y = __shfl_up(x, o); if ((t & 63) >= o) x += y; }
    __shared__ int ws[4];
    if ((t & 63) == 63) ws[t >> 6] = x;
    __syncthreads();
    int add = 0;
    for (int w = 0; w < (t >> 6); w++) add += ws[w];
    int incl = x + add;
    if (gid < n) offs[gid] = incl - v;
    if (t == 255) bsums[blockIdx.x] = incl;
}

__global__ __launch_bounds__(256)
void scan2_kernel(int* __restrict__ bsums, int nb) {
    int t = threadIdx.x;
    int v = (t < nb) ? bsums[t] : 0;
    int x = v;
#pragma unroll
    for (int o = 1; o < 64; o <<= 1) { int y = __shfl_up(x, o); if ((t & 63) >= o) x += y; }
    __shared__ int ws[4];
    if ((t & 63) == 63) ws[t >> 6] = x;
    __syncthreads();
    int add = 0;
    for (int w = 0; w < (t >> 6); w++) add += ws[w];
    if (t < nb) bsums[t] = x + add - v;
}

__global__ void scan3_kernel(int* __restrict__ offs, int* __restrict__ cursor,
                             const int* __restrict__ bsums, int n, int E) {
    int gid = blockIdx.x * 256 + threadIdx.x;
    if (gid < n) {
        int o = offs[gid] + bsums[blockIdx.x];
        offs[gid] = o;
        cursor[gid] = o;
    }
    if (gid == 0) offs[n] = E;
}

__global__ void scatter_kernel(const int* __restrict__ row, const int* __restrict__ col,
                               const float* __restrict__ val, int* __restrict__ cursor,
                               int2* __restrict__ edges, int E) {
    for (int e = blockIdx.x * blockDim.x + threadIdx.x; e < E; e += gridDim.x * blockDim.x) {
        int r = row[e];
        int p = atomicAdd(&cursor[r], 1);
        int2 ed;
        ed.x = col[e];
        ed.y = __float_as_int(val[e]);
        edges[p] = ed;
    }
}

// ============================ Sliced aggregation (XCD L2 locality) ============================
// 8 column-slices of F floats; slice = blockIdx&7 (round-robin XCD affinity -> each
// XCD's L2 only holds its 1/8 slice of S). Thread per node: serial edge loop,
// 2-edge unrolled (2 independent gather chains + packed 8B edge loads).
template <int F, bool WVS>
__global__ __launch_bounds__(256)
void aggS(const float* __restrict__ S, int ldS, const int* __restrict__ offs,
          const int2* __restrict__ edges, float* __restrict__ Aout, int ldO,
          float* __restrict__ vout, int n) {
    int slice = blockIdx.x & 7;
    int node  = (blockIdx.x >> 3) * 256 + threadIdx.x;
    if (node >= n) return;
    int soff = slice * F;
    int e0 = offs[node], e1 = offs[node + 1];

    float acc[F];
#pragma unroll
    for (int a = 0; a < F; a++) acc[a] = 0.f;
    float vsum = 0.f;

    int e = e0;
    for (; e + 2 <= e1; e += 2) {
        int2 ea = edges[e];
        int2 eb = edges[e + 1];
        const float* sa = S + (size_t)ea.x * ldS + soff;
        const float* sb = S + (size_t)eb.x * ldS + soff;
        float va = __int_as_float(ea.y);
        float vb = __int_as_float(eb.y);
        f4u ga[F / 4], gb[F / 4];
#pragma unroll
        for (int q = 0; q < F / 4; q++) ga[q] = *(const f4u*)(sa + 4 * q);
#pragma unroll
        for (int q = 0; q < F / 4; q++) gb[q] = *(const f4u*)(sb + 4 * q);
#pragma unroll
        for (int q = 0; q < F / 4; q++)
#pragma unroll
            for (int z = 0; z < 4; z++) {
                acc[4 * q + z] = fmaf(va, ga[q][z], acc[4 * q + z]);
                acc[4 * q + z] = fmaf(vb, gb[q][z], acc[4 * q + z]);
            }
        vsum += va + vb;
    }
    if (e < e1) {
        int2 ea = edges[e];
        const float* sa = S + (size_t)ea.x * ldS + soff;
        float va = __int_as_float(ea.y);
#pragma unroll
        for (int q = 0; q < F / 4; q++) {
            f4u g = *(const f4u*)(sa + 4 * q);
#pragma unroll
            for (int z = 0; z < 4; z++) acc[4 * q + z] = fmaf(va, g[z], acc[4 * q + z]);
        }
        vsum += va;
    }

    float* o = Aout + (size_t)node * ldO + soff;
#pragma unroll
    for (int q = 0; q < F / 4; q++) {
        f4u v;
#pragma unroll
        for (int z = 0; z < 4; z++) v[z] = acc[4 * q + z];
        *(f4u*)(o + 4 * q) = v;
    }
    if (WVS && slice == 0) vout[node] = vsum;
}

// ============================ Tiled GEMM: 64-row tile, chunked W ============================
template <int CT>
__device__ inline void ldw(const float* p, float* wv) {
    if constexpr (CT == 4) { *(f4a*)wv = *(const f4a*)p; }
    else if constexpr (CT == 6) { *(f3u*)wv = *(const f3u*)p; *(f3u*)(wv + 3) = *(const f3u*)(p + 3); }
    else { *(f4a*)wv = *(const f4a*)p; *(f4a*)(wv + 4) = *(const f4a*)(p + 4); }
}

template <int K, int C, bool DOBN, bool HASCB>
__global__ __launch_bounds__(256)
void gemmF(const float* __restrict__ A1, int ld1, int split,
           const float* __restrict__ A2, int ld2,
           const float* __restrict__ W, const float* __restrict__ bias,
           const float* __restrict__ cbv, const float* __restrict__ vsum,
           float* __restrict__ Out, float* __restrict__ bsum,
           float* __restrict__ bsumsq, int n) {
    constexpr int CT = C / 16;           // 4, 6, or 8
    __shared__ float Wc[16 * C];
    __shared__ float At[16][68];
    __shared__ float redS[DOBN ? C : 1];
    __shared__ float redQ[DOBN ? C : 1];

    int t  = threadIdx.x;
    int tc = t & 15, tr = t >> 4;
    int row0 = blockIdx.x * 64;

    if (DOBN && t < C) { redS[t] = 0.f; redQ[t] = 0.f; }

    int srow = t >> 2;
    int gr = row0 + srow; if (gr >= n) gr = n - 1;
    int kh = (t & 3) * 4;

    float acc[4][CT];
#pragma unroll
    for (int i = 0; i < 4; i++)
#pragma unroll
        for (int c = 0; c < CT; c++) acc[i][c] = 0.f;

    for (int kb = 0; kb < K; kb += 16) {
        __syncthreads();
        for (int i = t * 4; i < 16 * C; i += 1024)
            *(f4a*)&Wc[i] = *(const f4u*)&W[(size_t)kb * C + i];
        {
            int kg = kb + kh;
            const float* src = (kg < split) ? (A1 + (size_t)gr * ld1 + kg)
                                            : (A2 + (size_t)gr * ld2 + (kg - split));
            f4u v = *(const f4u*)src;
#pragma unroll
            for (int e = 0; e < 4; e++) At[kh + e][srow] = v[e];
        }
        __syncthreads();
#pragma unroll
        for (int kk = 0; kk < 16; kk++) {
            f4a av = *(const f4a*)&At[kk][tr * 4];
            float wv[CT];
            ldw<CT>(&Wc[kk * C + tc * CT], wv);
#pragma unroll
            for (int i = 0; i < 4; i++)
#pragma unroll
                for (int c = 0; c < CT; c++) acc[i][c] = fmaf(av[i], wv[c], acc[i][c]);
        }
    }

    float bb[CT], cc[CT];
#pragma unroll
    for (int c = 0; c < CT; c++) {
        bb[c] = bias[tc * CT + c];
        cc[c] = HASCB ? cbv[tc * CT + c] : 0.f;
    }
    float ps[CT], pq[CT];
#pragma unroll
    for (int c = 0; c < CT; c++) { ps[c] = 0.f; pq[c] = 0.f; }

#pragma unroll
    for (int i = 0; i < 4; i++) {
        int r = row0 + tr * 4 + i;
        if (r < n) {
            float vs = HASCB ? vsum[r] : 0.f;
            float* o = Out + (size_t)r * C + tc * CT;
#pragma unroll
            for (int c = 0; c < CT; c++) {
                float v = acc[i][c] + vs * cc[c] + bb[c];
                v = fmaxf(v, 0.f);
                o[c] = v;
                if (DOBN) { ps[c] += v; pq[c] += v * v; }
            }
        }
    }
    if (DOBN) {
#pragma unroll
        for (int c = 0; c < CT; c++) {
            ps[c] += __shfl_xor(ps[c], 16);
            ps[c] += __shfl_xor(ps[c], 32);
            pq[c] += __shfl_xor(pq[c], 16);
            pq[c] += __shfl_xor(pq[c], 32);
        }
        if ((t & 48) == 0) {
#pragma unroll
            for (int c = 0; c < CT; c++) {
                atomicAdd(&redS[tc * CT + c], ps[c]);
                atomicAdd(&redQ[tc * CT + c], pq[c]);
            }
        }
        __syncthreads();
        if (t < C) {
            atomicAdd(&bsum[t], redS[t]);
            atomicAdd(&bsumsq[t], redQ[t]);
        }
    }
}

// ============================ BN fold ============================
template <int C>
__global__ __launch_bounds__(256)
void fold_kernel(const float* __restrict__ W, float* __restrict__ bsum,
                 float* __restrict__ bsumsq, float* __restrict__ Wf,
                 float* __restrict__ cb, int N) {
    __shared__ float mean[96], inv[96];
    int t = threadIdx.x;
    float rn = 1.0f / (float)N;
    if (t < 96) {
        float mu  = bsum[t] * rn;
        float var = bsumsq[t] * rn - mu * mu;
        mean[t] = mu;
        inv[t]  = rsqrtf(var + 1e-5f);
        bsum[t] = 0.f;
        bsumsq[t] = 0.f;
    }
    __syncthreads();
    for (int i = t; i < 96 * C; i += 256) {
        int k = i / C;
        Wf[i] = inv[k] * W[i];
    }
    if (t < C) {
        float s = 0.f;
        for (int k = 0; k < 96; k++) s += mean[k] * inv[k] * W[k * C + t];
        cb[t] = -s;
    }
}

// ============================ final dot (64->1) + global min ============================
__global__ __launch_bounds__(256)
void dot_min_kernel(const float* __restrict__ A, const float* __restrict__ M3w,
                    const float* __restrict__ M3b, float* __restrict__ m,
                    unsigned* __restrict__ gmin, int n) {
    int lane = threadIdx.x & 63;
    int wv   = threadIdx.x >> 6;
    float w  = M3w[lane];
    float b  = M3b[0];
    float lmin = 3.4e38f;
    int nw = gridDim.x * 4;
    for (int r = blockIdx.x * 4 + wv; r < n; r += nw) {
        float v = A[(size_t)r * 64 + lane] * w;
#pragma unroll
        for (int o = 32; o; o >>= 1) v += __shfl_down(v, o);
        if (lane == 0) {
            float mv = v + b;
            m[r] = mv;
            lmin = fminf(lmin, mv);
        }
    }
#pragma unroll
    for (int o = 32; o; o >>= 1) lmin = fminf(lmin, __shfl_down(lmin, o));
    __shared__ float sm[4];
    if (lane == 0) sm[wv] = lmin;
    __syncthreads();
    if (threadIdx.x == 0) {
        float mn = fminf(fminf(sm[0], sm[1]), fminf(sm[2], sm[3]));
        unsigned u = __float_as_uint(mn);
        unsigned key = (u >> 31) ? ~u : (u | 0x80000000u);
        atomicMin(gmin, key);
    }
}

__global__ void where_kernel(const float* __restrict__ x, float* __restrict__ m,
                             const unsigned* __restrict__ gmin, int n) {
    int i = blockIdx.x * blockDim.x + threadIdx.x;
    if (i < n) {
        unsigned k = *gmin;
        unsigned u = (k >> 31) ? (k ^ 0x80000000u) : ~k;
        float g = __uint_as_float(u);
        if (x[(size_t)i * XLD + 160] == 0.0f) m[i] = g;
    }
}

// ============================ exact radix select ============================
__device__ inline unsigned fkey(float f) {
    unsigned u = __float_as_uint(f);
    return (u >> 31) ? ~u : (u | 0x80000000u);
}

__global__ __launch_bounds__(1024)
void select_kernel(const float* __restrict__ m, int n, int kwant, float* __restrict__ thresh) {
    __shared__ unsigned hist[256];
    __shared__ unsigned sprefix;
    __shared__ int skk;
    int t = threadIdx.x;
    if (t == 0) { sprefix = 0u; skk = kwant; }
    for (int pass = 0; pass < 4; ++pass) {
        if (t < 256) hist[t] = 0u;
        __syncthreads();
        int shift = 24 - 8 * pass;
        unsigned pfx = sprefix;
        for (int i = t; i < n; i += 1024) {
            unsigned key = fkey(m[i]);
            bool ok = (pass == 0) || ((key >> (shift + 8)) == (pfx >> (shift + 8)));
            if (ok) atomicAdd(&hist[(key >> shift) & 255u], 1u);
        }
        __syncthreads();
        if (t == 0) {
            int cum = 0, kk = skk, chosen = 0;
            for (int b = 255; b >= 0; b--) {
                cum += (int)hist[b];
                if (cum >= kk) { chosen = b; kk -= (cum - (int)hist[b]); break; }
            }
            sprefix = pfx | ((unsigned)chosen << shift);
            skk = kk;
        }
        __syncthreads();
    }
    if (t == 0) {
        unsigned key = sprefix;
        unsigned u = (key >> 31) ? (key ^ 0x80000000u) : ~key;
        *thresh = __uint_as_float(u);
    }
}

__global__ void mask_kernel(const float* __restrict__ m, const float* __restrict__ thresh,
                            float* __restrict__ out, int n) {
    int i = blockIdx.x * blockDim.x + threadIdx.x;
    if (i < n) {
        float t = *thresh, v = m[i];
        out[i] = (v > t) ? v * (1.0f / v) : 0.0f;
    }
}

// ============================ launch ============================
extern "C" void kernel_launch(void* const* d_in, const int* in_sizes, int n_in,
                              void* d_out, int out_size, void* d_ws, size_t ws_size,
                              hipStream_t stream) {
    const float* x   = (const float*)d_in[0];
    const int*   row = (const int*)d_in[1];
    const int*   col = (const int*)d_in[2];
    const float* val = (const float*)d_in[3];
    const float* W1  = (const float*)d_in[4];
    const float* b1  = (const float*)d_in[5];
    const float* W2  = (const float*)d_in[6];
    const float* b2  = (const float*)d_in[7];
    const float* W3  = (const float*)d_in[8];
    const float* b3  = (const float*)d_in[9];
    const float* W4  = (const float*)d_in[10];
    const float* b4  = (const float*)d_in[11];
    const float* W5  = (const float*)d_in[12];
    const float* b5  = (const float*)d_in[13];
    const float* M1w = (const float*)d_in[14];
    const float* M1b = (const float*)d_in[15];
    const float* M2w = (const float*)d_in[16];
    const float* M2b = (const float*)d_in[17];
    const float* M3w = (const float*)d_in[18];
    const float* M3b = (const float*)d_in[19];

    const int n = in_sizes[0] / XLD;   // 50000
    const int E = in_sizes[1];         // 800000

    char* ws = (char*)d_ws;
    size_t off = 0;
    auto carve = [&](size_t bytes) -> void* {
        void* p = ws + off;
        off = (off + bytes + 255) & ~(size_t)255;
        return p;
    };
    int*      offs   = (int*)carve((size_t)(n + 1) * 4);
    int*      cursor = (int*)carve((size_t)n * 4);
    int*      bsums  = (int*)carve(256 * 4);
    int2*     edges  = (int2*)carve((size_t)E * 8);
    float*    h      = (float*)carve((size_t)n * 96 * 4);
    float*    big    = (float*)carve((size_t)n * 128 * 4);
    float*    Wf     = (float*)carve(96 * 96 * 4);
    float*    stats  = (float*)carve(192 * 4);
    float*    cb     = (float*)carve(96 * 4);
    float*    vsum   = (float*)carve((size_t)n * 4);
    float*    m      = (float*)carve((size_t)n * 4);
    unsigned* gmin   = (unsigned*)carve(4);
    float*    thresh = (float*)carve(4);
    float* bsum   = stats;
    float* bsumsq = stats + 96;

    hipMemsetAsync(cursor, 0, (size_t)n * 4, stream);
    hipMemsetAsync(stats, 0, 192 * 4, stream);
    hipMemsetAsync(gmin, 0xFF, 4, stream);

    // CSR build
    const int nb = (n + 255) / 256;
    hist_kernel<<<512, 256, 0, stream>>>(row, cursor, E);
    scan1_kernel<<<nb, 256, 0, stream>>>(cursor, offs, bsums, n);
    scan2_kernel<<<1, 256, 0, stream>>>(bsums, nb);
    scan3_kernel<<<nb, 256, 0, stream>>>(offs, cursor, bsums, n, E);
    scatter_kernel<<<512, 256, 0, stream>>>(row, col, val, cursor, edges, E);

    const int gB = (n + 63) / 64;       // gemmF row tiles (782)
    const int gS = nb * 8;              // sliced agg: 8 slices x node-blocks

    // Layer 1: aggX = agg(x[:, :128]) (+vsum); h1 = relu(aggX@W1 + b1), BN stats
    aggS<16, true><<<gS, 256, 0, stream>>>(x, XLD, offs, edges, big, 128, vsum, n);
    gemmF<128, 96, true, false><<<gB, 256, 0, stream>>>(big, 128, 128, big, 128,
        W1, b1, nullptr, nullptr, h, bsum, bsumsq, n);

    // Layers 2-4
    fold_kernel<96><<<1, 256, 0, stream>>>(W2, bsum, bsumsq, Wf, cb, n);
    aggS<12, false><<<gS, 256, 0, stream>>>(h, 96, offs, edges, big, 96, nullptr, n);
    gemmF<96, 96, true, true><<<gB, 256, 0, stream>>>(big, 96, 96, big, 96,
        Wf, b2, cb, vsum, h, bsum, bsumsq, n);

    fold_kernel<96><<<1, 256, 0, stream>>>(W3, bsum, bsumsq, Wf, cb, n);
    aggS<12, false><<<gS, 256, 0, stream>>>(h, 96, offs, edges, big, 96, nullptr, n);
    gemmF<96, 96, true, true><<<gB, 256, 0, stream>>>(big, 96, 96, big, 96,
        Wf, b3, cb, vsum, h, bsum, bsumsq, n);

    fold_kernel<96><<<1, 256, 0, stream>>>(W4, bsum, bsumsq, Wf, cb, n);
    aggS<12, false><<<gS, 256, 0, stream>>>(h, 96, offs, edges, big, 96, nullptr, n);
    gemmF<96, 96, true, true><<<gB, 256, 0, stream>>>(big, 96, 96, big, 96,
        Wf, b4, cb, vsum, h, bsum, bsumsq, n);

    // Layer 5 (96 -> 64, no BN stats after)
    fold_kernel<64><<<1, 256, 0, stream>>>(W5, bsum, bsumsq, Wf, cb, n);
    aggS<12, false><<<gS, 256, 0, stream>>>(h, 96, offs, edges, big, 96, nullptr, n);
    gemmF<96, 64, false, true><<<gB, 256, 0, stream>>>(big, 96, 96, big, 96,
        Wf, b5, cb, vsum, h, bsum, bsumsq, n);

    // MLP
    gemmF<96, 128, false, false><<<gB, 256, 0, stream>>>(h, 64, 64, x + 128, XLD,
        M1w, M1b, nullptr, nullptr, big, bsum, bsumsq, n);
    gemmF<128, 64, false, false><<<gB, 256, 0, stream>>>(big, 128, 128, big, 128,
        M2w, M2b, nullptr, nullptr, h, bsum, bsumsq, n);

    // m = a2 @ M3w + M3b ; global min
    dot_min_kernel<<<256, 256, 0, stream>>>(h, M3w, M3b, m, gmin, n);

    // where(grp==0, min, m)
    where_kernel<<<(n + 255) / 256, 256, 0, stream>>>(x, m, gmin, n);

    // exact 71st-largest threshold
    select_kernel<<<1, 1024, 0, stream>>>(m, n, 71, thresh);

    // out = m>thresh ? m*(1/m) : 0
    mask_kernel<<<(n + 255) / 256, 256, 0, stream>>>(m, thresh, (float*)d_out, n);
}

// Round 8
// 1462.332 us; speedup vs baseline: 1.0454x; 1.0454x over previous
//
#include <hip/hip_runtime.h>
#include <cstdint>
#include <cstddef>

#define XLD 161   // x row stride = NFEAT + EXTRA + 1

typedef float f4u __attribute__((ext_vector_type(4), aligned(4)));  // unaligned-tolerant
typedef float f4a __attribute__((ext_vector_type(4)));              // 16B-aligned
typedef float f3u __attribute__((ext_vector_type(3), aligned(4)));

// ============================ CSR build ============================
__global__ void hist_kernel(const int* __restrict__ row, int* __restrict__ cnt, int E) {
    for (int e = blockIdx.x * blockDim.x + threadIdx.x; e < E; e += gridDim.x * blockDim.x)
        atomicAdd(&cnt[row[e]], 1);
}

__global__ __launch_bounds__(256)
void scan1_kernel(const int* __restrict__ cnt, int* __restrict__ offs,
                  int* __restrict__ bsums, int n) {
    int t = threadIdx.x;
    int gid = blockIdx.x * 256 + t;
    int v = (gid < n) ? cnt[gid] : 0;
    int x = v;
#pragma unroll
    for (int o = 1; o < 64; o <<= 1) { int y = __shfl_up(x, o); if ((t & 63) >= o) x += y; }
    __shared__ int ws[4];
    if ((t & 63) == 63) ws[t >> 6] = x;
    __syncthreads();
    int add = 0;
    for (int w = 0; w < (t >> 6); w++) add += ws[w];
    int incl = x + add;
    if (gid < n) offs[gid] = incl - v;
    if (t == 255) bsums[blockIdx.x] = incl;
}

__global__ __launch_bounds__(256)
void scan2_kernel(int* __restrict__ bsums, int nb) {
    int t = threadIdx.x;
    int v = (t < nb) ? bsums[t] : 0;
    int x = v;
#pragma unroll
    for (int o = 1; o < 64; o <<= 1) { int y = __shfl_up(x, o); if ((t & 63) >= o) x += y; }
    __shared__ int ws[4];
    if ((t & 63) == 63) ws[t >> 6] = x;
    __syncthreads();
    int add = 0;
    for (int w = 0; w < (t >> 6); w++) add += ws[w];
    if (t < nb) bsums[t] = x + add - v;
}

__global__ void scan3_kernel(int* __restrict__ offs, int* __restrict__ cursor,
                             const int* __restrict__ bsums, int n, int E) {
    int gid = blockIdx.x * 256 + threadIdx.x;
    if (gid < n) {
        int o = offs[gid] + bsums[blockIdx.x];
        offs[gid] = o;
        cursor[gid] = o;
    }
    if (gid == 0) offs[n] = E;
}

__global__ void scatter_kernel(const int* __restrict__ row, const int* __restrict__ col,
                               const float* __restrict__ val, int* __restrict__ cursor,
                               int2* __restrict__ edges, int E) {
    for (int e = blockIdx.x * blockDim.x + threadIdx.x; e < E; e += gridDim.x * blockDim.x) {
        int r = row[e];
        int p = atomicAdd(&cursor[r], 1);
        int2 ed;
        ed.x = col[e];
        ed.y = __float_as_int(val[e]);
        edges[p] = ed;
    }
}

// ============================ helpers ============================
template <int CT>
__device__ inline void ldw(const float* p, float* wv) {
    if constexpr (CT == 4) { *(f4a*)wv = *(const f4a*)p; }
    else if constexpr (CT == 6) { *(f3u*)wv = *(const f3u*)p; *(f3u*)(wv + 3) = *(const f3u*)(p + 3); }
    else { *(f4a*)wv = *(const f4a*)p; *(f4a*)(wv + 4) = *(const f4a*)(p + 4); }
}

// ============================ Fused layer: gather -> LDS -> GEMM -> epilogue ============================
// Block = 256 threads = 8 groups x 32 lanes; handles 64 nodes (group g: locals g*8..g*8+7).
// Phase 1 (gather): aggP-style shfl-broadcast edge loop; lane lg owns features
// k = lg + 32a (strided), writes transposed into LDS At[k][local] (4-way conflicts only).
// vsum (graph-invariant) recomputed into vsL.
// Phase 2 (gemm): Out[n x C] = relu( At^T @ W + vsum*cb + bias ), chunked-W LDS staging,
// optional BN stats (wave shfl reduce -> LDS -> per-block global atomics).
template <int LC, int C, bool DOBN, bool HASCB>
__global__ __launch_bounds__(256)
void fusedL(const float* __restrict__ S, int ldS,
            const int* __restrict__ offs, const int2* __restrict__ edges,
            const float* __restrict__ W, const float* __restrict__ bias,
            const float* __restrict__ cbv,
            float* __restrict__ Hout,
            float* __restrict__ bsum, float* __restrict__ bsumsq, int n) {
    constexpr int K = 32 * LC;
    constexpr int CT = C / 16;           // 4 or 6
    __shared__ float At[K][68];
    __shared__ float Wc[16 * C];
    __shared__ float vsL[64];
    __shared__ float redS[DOBN ? C : 1];
    __shared__ float redQ[DOBN ? C : 1];

    int t   = threadIdx.x;
    int lg  = t & 31;
    int sh  = t & 32;
    int grp = t >> 5;
    int row0 = blockIdx.x * 64;
    if (DOBN && t < C) { redS[t] = 0.f; redQ[t] = 0.f; }

    // ---------------- gather phase ----------------
    for (int i = 0; i < 8; i++) {
        int local = grp * 8 + i;
        int node  = row0 + local;
        float acc[LC];
#pragma unroll
        for (int a = 0; a < LC; a++) acc[a] = 0.f;
        float vsum = 0.f;
        if (node < n) {
            int e0 = offs[node], e1 = offs[node + 1];
            for (int e = e0; e < e1; e += 32) {
                int idx = e + lg;
                int2 ed = (idx < e1) ? edges[idx] : make_int2(0, 0);
                int cnt = min(32, e1 - e);
#pragma unroll 8
                for (int j = 0; j < cnt; j++) {
                    int   c = __shfl(ed.x, sh + j);
                    float v = __int_as_float(__shfl(ed.y, sh + j));
                    const float* srow = S + (size_t)c * ldS + lg;
#pragma unroll
                    for (int a = 0; a < LC; a++) acc[a] = fmaf(v, srow[32 * a], acc[a]);
                    vsum += v;
                }
            }
        }
#pragma unroll
        for (int a = 0; a < LC; a++) At[lg + 32 * a][local] = acc[a];
        if (lg == 0) vsL[local] = vsum;
    }
    __syncthreads();

    // ---------------- gemm phase ----------------
    int tc = t & 15, tr = t >> 4;
    float acc[4][CT];
#pragma unroll
    for (int i = 0; i < 4; i++)
#pragma unroll
        for (int c = 0; c < CT; c++) acc[i][c] = 0.f;

    for (int kb = 0; kb < K; kb += 16) {
        if (kb) __syncthreads();
        for (int i4 = t * 4; i4 < 16 * C; i4 += 1024)
            *(f4a*)&Wc[i4] = *(const f4u*)&W[(size_t)kb * C + i4];
        __syncthreads();
#pragma unroll
        for (int kk = 0; kk < 16; kk++) {
            f4a av = *(const f4a*)&At[kb + kk][tr * 4];
            float wv[CT];
            ldw<CT>(&Wc[kk * C + tc * CT], wv);
#pragma unroll
            for (int i = 0; i < 4; i++)
#pragma unroll
                for (int c = 0; c < CT; c++) acc[i][c] = fmaf(av[i], wv[c], acc[i][c]);
        }
    }

    // ---------------- epilogue ----------------
    float bb[CT], cc[CT];
#pragma unroll
    for (int c = 0; c < CT; c++) {
        bb[c] = bias[tc * CT + c];
        cc[c] = HASCB ? cbv[tc * CT + c] : 0.f;
    }
    float ps[CT], pq[CT];
#pragma unroll
    for (int c = 0; c < CT; c++) { ps[c] = 0.f; pq[c] = 0.f; }

#pragma unroll
    for (int i = 0; i < 4; i++) {
        int local = tr * 4 + i;
        int r = row0 + local;
        if (r < n) {
            float vs = HASCB ? vsL[local] : 0.f;
            float* o = Hout + (size_t)r * C + tc * CT;
#pragma unroll
            for (int c = 0; c < CT; c++) {
                float v = acc[i][c] + vs * cc[c] + bb[c];
                v = fmaxf(v, 0.f);
                o[c] = v;
                if (DOBN) { ps[c] += v; pq[c] += v * v; }
            }
        }
    }
    if (DOBN) {
#pragma unroll
        for (int c = 0; c < CT; c++) {
            ps[c] += __shfl_xor(ps[c], 16);
            ps[c] += __shfl_xor(ps[c], 32);
            pq[c] += __shfl_xor(pq[c], 16);
            pq[c] += __shfl_xor(pq[c], 32);
        }
        if ((t & 48) == 0) {
#pragma unroll
            for (int c = 0; c < CT; c++) {
                atomicAdd(&redS[tc * CT + c], ps[c]);
                atomicAdd(&redQ[tc * CT + c], pq[c]);
            }
        }
        __syncthreads();
        if (t < C) {
            atomicAdd(&bsum[t], redS[t]);
            atomicAdd(&bsumsq[t], redQ[t]);
        }
    }
}

// ============================ Tiled GEMM (MLP): 64-row tile, chunked W ============================
template <int K, int C, bool DOBN, bool HASCB>
__global__ __launch_bounds__(256)
void gemmF(const float* __restrict__ A1, int ld1, int split,
           const float* __restrict__ A2, int ld2,
           const float* __restrict__ W, const float* __restrict__ bias,
           const float* __restrict__ cbv, const float* __restrict__ vsum,
           float* __restrict__ Out, float* __restrict__ bsum,
           float* __restrict__ bsumsq, int n) {
    constexpr int CT = C / 16;
    __shared__ float Wc[16 * C];
    __shared__ float At[16][68];
    __shared__ float redS[DOBN ? C : 1];
    __shared__ float redQ[DOBN ? C : 1];

    int t  = threadIdx.x;
    int tc = t & 15, tr = t >> 4;
    int row0 = blockIdx.x * 64;

    if (DOBN && t < C) { redS[t] = 0.f; redQ[t] = 0.f; }

    int srow = t >> 2;
    int gr = row0 + srow; if (gr >= n) gr = n - 1;
    int kh = (t & 3) * 4;

    float acc[4][CT];
#pragma unroll
    for (int i = 0; i < 4; i++)
#pragma unroll
        for (int c = 0; c < CT; c++) acc[i][c] = 0.f;

    for (int kb = 0; kb < K; kb += 16) {
        __syncthreads();
        for (int i = t * 4; i < 16 * C; i += 1024)
            *(f4a*)&Wc[i] = *(const f4u*)&W[(size_t)kb * C + i];
        {
            int kg = kb + kh;
            const float* src = (kg < split) ? (A1 + (size_t)gr * ld1 + kg)
                                            : (A2 + (size_t)gr * ld2 + (kg - split));
            f4u v = *(const f4u*)src;
#pragma unroll
            for (int e = 0; e < 4; e++) At[kh + e][srow] = v[e];
        }
        __syncthreads();
#pragma unroll
        for (int kk = 0; kk < 16; kk++) {
            f4a av = *(const f4a*)&At[kk][tr * 4];
            float wv[CT];
            ldw<CT>(&Wc[kk * C + tc * CT], wv);
#pragma unroll
            for (int i = 0; i < 4; i++)
#pragma unroll
                for (int c = 0; c < CT; c++) acc[i][c] = fmaf(av[i], wv[c], acc[i][c]);
        }
    }

    float bb[CT], cc[CT];
#pragma unroll
    for (int c = 0; c < CT; c++) {
        bb[c] = bias[tc * CT + c];
        cc[c] = HASCB ? cbv[tc * CT + c] : 0.f;
    }

#pragma unroll
    for (int i = 0; i < 4; i++) {
        int r = row0 + tr * 4 + i;
        if (r < n) {
            float vs = HASCB ? vsum[r] : 0.f;
            float* o = Out + (size_t)r * C + tc * CT;
#pragma unroll
            for (int c = 0; c < CT; c++) {
                float v = acc[i][c] + vs * cc[c] + bb[c];
                v = fmaxf(v, 0.f);
                o[c] = v;
            }
        }
    }
}

// ============================ BN fold ============================
template <int C>
__global__ __launch_bounds__(256)
void fold_kernel(const float* __restrict__ W, float* __restrict__ bsum,
                 float* __restrict__ bsumsq, float* __restrict__ Wf,
                 float* __restrict__ cb, int N) {
    __shared__ float mean[96], inv[96];
    int t = threadIdx.x;
    float rn = 1.0f / (float)N;
    if (t < 96) {
        float mu  = bsum[t] * rn;
        float var = bsumsq[t] * rn - mu * mu;
        mean[t] = mu;
        inv[t]  = rsqrtf(var + 1e-5f);
        bsum[t] = 0.f;
        bsumsq[t] = 0.f;
    }
    __syncthreads();
    for (int i = t; i < 96 * C; i += 256) {
        int k = i / C;
        Wf[i] = inv[k] * W[i];
    }
    if (t < C) {
        float s = 0.f;
        for (int k = 0; k < 96; k++) s += mean[k] * inv[k] * W[k * C + t];
        cb[t] = -s;
    }
}

// ============================ final dot (64->1) + global min ============================
__global__ __launch_bounds__(256)
void dot_min_kernel(const float* __restrict__ A, const float* __restrict__ M3w,
                    const float* __restrict__ M3b, float* __restrict__ m,
                    unsigned* __restrict__ gmin, int n) {
    int lane = threadIdx.x & 63;
    int wv   = threadIdx.x >> 6;
    float w  = M3w[lane];
    float b  = M3b[0];
    float lmin = 3.4e38f;
    int nw = gridDim.x * 4;
    for (int r = blockIdx.x * 4 + wv; r < n; r += nw) {
        float v = A[(size_t)r * 64 + lane] * w;
#pragma unroll
        for (int o = 32; o; o >>= 1) v += __shfl_down(v, o);
        if (lane == 0) {
            float mv = v + b;
            m[r] = mv;
            lmin = fminf(lmin, mv);
        }
    }
#pragma unroll
    for (int o = 32; o; o >>= 1) lmin = fminf(lmin, __shfl_down(lmin, o));
    __shared__ float sm[4];
    if (lane == 0) sm[wv] = lmin;
    __syncthreads();
    if (threadIdx.x == 0) {
        float mn = fminf(fminf(sm[0], sm[1]), fminf(sm[2], sm[3]));
        unsigned u = __float_as_uint(mn);
        unsigned key = (u >> 31) ? ~u : (u | 0x80000000u);
        atomicMin(gmin, key);
    }
}

__global__ void where_kernel(const float* __restrict__ x, float* __restrict__ m,
                             const unsigned* __restrict__ gmin, int n) {
    int i = blockIdx.x * blockDim.x + threadIdx.x;
    if (i < n) {
        unsigned k = *gmin;
        unsigned u = (k >> 31) ? (k ^ 0x80000000u) : ~k;
        float g = __uint_as_float(u);
        if (x[(size_t)i * XLD + 160] == 0.0f) m[i] = g;
    }
}

// ============================ exact radix select ============================
__device__ inline unsigned fkey(float f) {
    unsigned u = __float_as_uint(f);
    return (u >> 31) ? ~u : (u | 0x80000000u);
}

__global__ __launch_bounds__(1024)
void select_kernel(const float* __restrict__ m, int n, int kwant, float* __restrict__ thresh) {
    __shared__ unsigned hist[256];
    __shared__ unsigned sprefix;
    __shared__ int skk;
    int t = threadIdx.x;
    if (t == 0) { sprefix = 0u; skk = kwant; }
    for (int pass = 0; pass < 4; ++pass) {
        if (t < 256) hist[t] = 0u;
        __syncthreads();
        int shift = 24 - 8 * pass;
        unsigned pfx = sprefix;
        for (int i = t; i < n; i += 1024) {
            unsigned key = fkey(m[i]);
            bool ok = (pass == 0) || ((key >> (shift + 8)) == (pfx >> (shift + 8)));
            if (ok) atomicAdd(&hist[(key >> shift) & 255u], 1u);
        }
        __syncthreads();
        if (t == 0) {
            int cum = 0, kk = skk, chosen = 0;
            for (int b = 255; b >= 0; b--) {
                cum += (int)hist[b];
                if (cum >= kk) { chosen = b; kk -= (cum - (int)hist[b]); break; }
            }
            sprefix = pfx | ((unsigned)chosen << shift);
            skk = kk;
        }
        __syncthreads();
    }
    if (t == 0) {
        unsigned key = sprefix;
        unsigned u = (key >> 31) ? (key ^ 0x80000000u) : ~key;
        *thresh = __uint_as_float(u);
    }
}

__global__ void mask_kernel(const float* __restrict__ m, const float* __restrict__ thresh,
                            float* __restrict__ out, int n) {
    int i = blockIdx.x * blockDim.x + threadIdx.x;
    if (i < n) {
        float t = *thresh, v = m[i];
        out[i] = (v > t) ? v * (1.0f / v) : 0.0f;
    }
}

// ============================ launch ============================
extern "C" void kernel_launch(void* const* d_in, const int* in_sizes, int n_in,
                              void* d_out, int out_size, void* d_ws, size_t ws_size,
                              hipStream_t stream) {
    const float* x   = (const float*)d_in[0];
    const int*   row = (const int*)d_in[1];
    const int*   col = (const int*)d_in[2];
    const float* val = (const float*)d_in[3];
    const float* W1  = (const float*)d_in[4];
    const float* b1  = (const float*)d_in[5];
    const float* W2  = (const float*)d_in[6];
    const float* b2  = (const float*)d_in[7];
    const float* W3  = (const float*)d_in[8];
    const float* b3  = (const float*)d_in[9];
    const float* W4  = (const float*)d_in[10];
    const float* b4  = (const float*)d_in[11];
    const float* W5  = (const float*)d_in[12];
    const float* b5  = (const float*)d_in[13];
    const float* M1w = (const float*)d_in[14];
    const float* M1b = (const float*)d_in[15];
    const float* M2w = (const float*)d_in[16];
    const float* M2b = (const float*)d_in[17];
    const float* M3w = (const float*)d_in[18];
    const float* M3b = (const float*)d_in[19];

    const int n = in_sizes[0] / XLD;   // 50000
    const int E = in_sizes[1];         // 800000

    char* ws = (char*)d_ws;
    size_t off = 0;
    auto carve = [&](size_t bytes) -> void* {
        void* p = ws + off;
        off = (off + bytes + 255) & ~(size_t)255;
        return p;
    };
    int*      offs   = (int*)carve((size_t)(n + 1) * 4);
    int*      cursor = (int*)carve((size_t)n * 4);
    int*      bsums  = (int*)carve(256 * 4);
    int2*     edges  = (int2*)carve((size_t)E * 8);
    float*    h      = (float*)carve((size_t)n * 96 * 4);   // ping
    float*    big    = (float*)carve((size_t)n * 128 * 4);  // pong / MLP a1
    float*    Wf     = (float*)carve(96 * 96 * 4);
    float*    stats  = (float*)carve(192 * 4);
    float*    cb     = (float*)carve(96 * 4);
    float*    m      = (float*)carve((size_t)n * 4);
    unsigned* gmin   = (unsigned*)carve(4);
    float*    thresh = (float*)carve(4);
    float* bsum   = stats;
    float* bsumsq = stats + 96;

    hipMemsetAsync(cursor, 0, (size_t)n * 4, stream);
    hipMemsetAsync(stats, 0, 192 * 4, stream);
    hipMemsetAsync(gmin, 0xFF, 4, stream);

    // CSR build
    const int nb = (n + 255) / 256;
    hist_kernel<<<512, 256, 0, stream>>>(row, cursor, E);
    scan1_kernel<<<nb, 256, 0, stream>>>(cursor, offs, bsums, n);
    scan2_kernel<<<1, 256, 0, stream>>>(bsums, nb);
    scan3_kernel<<<nb, 256, 0, stream>>>(offs, cursor, bsums, n, E);
    scatter_kernel<<<512, 256, 0, stream>>>(row, col, val, cursor, edges, E);

    const int gF = (n + 63) / 64;       // 782 fused/gemm tiles

    // Layer 1: gather x[:, :128] -> h1 = relu(agg@W1 + b1), BN stats
    fusedL<4, 96, true, false><<<gF, 256, 0, stream>>>(x, XLD, offs, edges,
        W1, b1, nullptr, h, bsum, bsumsq, n);

    // Layer 2: h -> big
    fold_kernel<96><<<1, 256, 0, stream>>>(W2, bsum, bsumsq, Wf, cb, n);
    fusedL<3, 96, true, true><<<gF, 256, 0, stream>>>(h, 96, offs, edges,
        Wf, b2, cb, big, bsum, bsumsq, n);

    // Layer 3: big -> h
    fold_kernel<96><<<1, 256, 0, stream>>>(W3, bsum, bsumsq, Wf, cb, n);
    fusedL<3, 96, true, true><<<gF, 256, 0, stream>>>(big, 96, offs, edges,
        Wf, b3, cb, h, bsum, bsumsq, n);

    // Layer 4: h -> big
    fold_kernel<96><<<1, 256, 0, stream>>>(W4, bsum, bsumsq, Wf, cb, n);
    fusedL<3, 96, true, true><<<gF, 256, 0, stream>>>(h, 96, offs, edges,
        Wf, b4, cb, big, bsum, bsumsq, n);

    // Layer 5: big -> h (n x 64), no BN stats
    fold_kernel<64><<<1, 256, 0, stream>>>(W5, bsum, bsumsq, Wf, cb, n);
    fusedL<3, 64, false, true><<<gF, 256, 0, stream>>>(big, 96, offs, edges,
        Wf, b5, cb, h, bsum, bsumsq, n);

    // MLP: a1 = relu([h5 | x[:,128:160]] @ M1w + M1b) -> big (n x 128)
    gemmF<96, 128, false, false><<<gF, 256, 0, stream>>>(h, 64, 64, x + 128, XLD,
        M1w, M1b, nullptr, nullptr, big, bsum, bsumsq, n);
    // a2 = relu(a1 @ M2w + M2b) -> h (n x 64)
    gemmF<128, 64, false, false><<<gF, 256, 0, stream>>>(big, 128, 128, big, 128,
        M2w, M2b, nullptr, nullptr, h, bsum, bsumsq, n);

    // m = a2 @ M3w + M3b ; global min
    dot_min_kernel<<<256, 256, 0, stream>>>(h, M3w, M3b, m, gmin, n);

    // where(grp==0, min, m)
    where_kernel<<<(n + 255) / 256, 256, 0, stream>>>(x, m, gmin, n);

    // exact 71st-largest threshold
    select_kernel<<<1, 1024, 0, stream>>>(m, n, 71, thresh);

    // out = m>thresh ? m*(1/m) : 0
    mask_kernel<<<(n + 255) / 256, 256, 0, stream>>>(m, thresh, (float*)d_out, n);
}

// Round 9
// 870.108 us; speedup vs baseline: 1.7569x; 1.6806x over previous
//
#include <hip/hip_runtime.h>
#include <cstdint>
#include <cstddef>

#define XLD 161   // x row stride = NFEAT + EXTRA + 1

typedef float f4u __attribute__((ext_vector_type(4), aligned(4)));  // unaligned-tolerant
typedef float f4a __attribute__((ext_vector_type(4)));              // 16B-aligned
typedef float f3u __attribute__((ext_vector_type(3), aligned(4)));

// ============================ CSR build ============================
__global__ void hist_kernel(const int* __restrict__ row, int* __restrict__ cnt, int E) {
    for (int e = blockIdx.x * blockDim.x + threadIdx.x; e < E; e += gridDim.x * blockDim.x)
        atomicAdd(&cnt[row[e]], 1);
}

__global__ __launch_bounds__(256)
void scan1_kernel(const int* __restrict__ cnt, int* __restrict__ offs,
                  int* __restrict__ bsums, int n) {
    int t = threadIdx.x;
    int gid = blockIdx.x * 256 + t;
    int v = (gid < n) ? cnt[gid] : 0;
    int x = v;
#pragma unroll
    for (int o = 1; o < 64; o <<= 1) { int y = __shfl_up(x, o); if ((t & 63) >= o) x += y; }
    __shared__ int ws[4];
    if ((t & 63) == 63) ws[t >> 6] = x;
    __syncthreads();
    int add = 0;
    for (int w = 0; w < (t >> 6); w++) add += ws[w];
    int incl = x + add;
    if (gid < n) offs[gid] = incl - v;
    if (t == 255) bsums[blockIdx.x] = incl;
}

__global__ __launch_bounds__(256)
void scan2_kernel(int* __restrict__ bsums, int nb) {
    int t = threadIdx.x;
    int v = (t < nb) ? bsums[t] : 0;
    int x = v;
#pragma unroll
    for (int o = 1; o < 64; o <<= 1) { int y = __shfl_up(x, o); if ((t & 63) >= o) x += y; }
    __shared__ int ws[4];
    if ((t & 63) == 63) ws[t >> 6] = x;
    __syncthreads();
    int add = 0;
    for (int w = 0; w < (t >> 6); w++) add += ws[w];
    if (t < nb) bsums[t] = x + add - v;
}

__global__ void scan3_kernel(int* __restrict__ offs, int* __restrict__ cursor,
                             const int* __restrict__ bsums, int n, int E) {
    int gid = blockIdx.x * 256 + threadIdx.x;
    if (gid < n) {
        int o = offs[gid] + bsums[blockIdx.x];
        offs[gid] = o;
        cursor[gid] = o;
    }
    if (gid == 0) offs[n] = E;
}

__global__ void scatter_kernel(const int* __restrict__ row, const int* __restrict__ col,
                               const float* __restrict__ val, int* __restrict__ cursor,
                               int2* __restrict__ edges, int E) {
    for (int e = blockIdx.x * blockDim.x + threadIdx.x; e < E; e += gridDim.x * blockDim.x) {
        int r = row[e];
        int p = atomicAdd(&cursor[r], 1);
        int2 ed;
        ed.x = col[e];
        ed.y = __float_as_int(val[e]);
        edges[p] = ed;
    }
}

// ============================ helpers ============================
template <int CT>
__device__ inline void ldw(const float* p, float* wv) {
    if constexpr (CT == 4) { *(f4a*)wv = *(const f4a*)p; }
    else if constexpr (CT == 6) { *(f3u*)wv = *(const f3u*)p; *(f3u*)(wv + 3) = *(const f3u*)(p + 3); }
    else { *(f4a*)wv = *(const f4a*)p; *(f4a*)(wv + 4) = *(const f4a*)(p + 4); }
}

// ============================ Fused layer: gather -> LDS -> GEMM -> epilogue ============================
// Block = 256 threads = 8 groups x 32 lanes; 64 nodes (group g: locals g*8..g*8+7).
// Gather phase: shfl-broadcast edge loop (aggP pattern); lane lg owns features k=lg+32a,
// writes transposed into LDS At[k][local]. NOTE: the node loop MUST NOT be unrolled —
// unrolling keeps 8 nodes of gather state live -> 256 VGPR + scratch spill (R8: 446 MB
// spill writes). vsum (graph-invariant) recomputed into vsL.
// Gemm phase: Out = relu(At^T @ W + vsum*cb + bias), chunked-W staging, BN stats optional.
template <int LC, int C, bool DOBN, bool HASCB>
__global__ __launch_bounds__(256)
void fusedL(const float* __restrict__ S, int ldS,
            const int* __restrict__ offs, const int2* __restrict__ edges,
            const float* __restrict__ W, const float* __restrict__ bias,
            const float* __restrict__ cbv,
            float* __restrict__ Hout,
            float* __restrict__ bsum, float* __restrict__ bsumsq, int n) {
    constexpr int K = 32 * LC;
    constexpr int CT = C / 16;           // 4 or 6
    __shared__ float At[K][68];
    __shared__ float Wc[16 * C];
    __shared__ float vsL[64];
    __shared__ float redS[DOBN ? C : 1];
    __shared__ float redQ[DOBN ? C : 1];

    int t   = threadIdx.x;
    int lg  = t & 31;
    int sh  = t & 32;
    int grp = t >> 5;
    int row0 = blockIdx.x * 64;
    if (DOBN && t < C) { redS[t] = 0.f; redQ[t] = 0.f; }

    // ---------------- gather phase ----------------
#pragma unroll 1
    for (int i = 0; i < 8; i++) {
        int local = grp * 8 + i;
        int node  = row0 + local;
        float acc[LC];
#pragma unroll
        for (int a = 0; a < LC; a++) acc[a] = 0.f;
        float vsum = 0.f;
        if (node < n) {
            int e0 = offs[node], e1 = offs[node + 1];
#pragma unroll 1
            for (int e = e0; e < e1; e += 32) {
                int idx = e + lg;
                int2 ed = (idx < e1) ? edges[idx] : make_int2(0, 0);
                int cnt = min(32, e1 - e);
#pragma unroll 8
                for (int j = 0; j < cnt; j++) {
                    int   c = __shfl(ed.x, sh + j);
                    float v = __int_as_float(__shfl(ed.y, sh + j));
                    const float* srow = S + (size_t)c * ldS + lg;
#pragma unroll
                    for (int a = 0; a < LC; a++) acc[a] = fmaf(v, srow[32 * a], acc[a]);
                    vsum += v;
                }
            }
        }
#pragma unroll
        for (int a = 0; a < LC; a++) At[lg + 32 * a][local] = acc[a];
        if (lg == 0) vsL[local] = vsum;
    }
    __syncthreads();

    // ---------------- gemm phase ----------------
    int tc = t & 15, tr = t >> 4;
    float acc[4][CT];
#pragma unroll
    for (int i = 0; i < 4; i++)
#pragma unroll
        for (int c = 0; c < CT; c++) acc[i][c] = 0.f;

#pragma unroll 1
    for (int kb = 0; kb < K; kb += 16) {
        if (kb) __syncthreads();
        for (int i4 = t * 4; i4 < 16 * C; i4 += 1024)
            *(f4a*)&Wc[i4] = *(const f4u*)&W[(size_t)kb * C + i4];
        __syncthreads();
#pragma unroll
        for (int kk = 0; kk < 16; kk++) {
            f4a av = *(const f4a*)&At[kb + kk][tr * 4];
            float wv[CT];
            ldw<CT>(&Wc[kk * C + tc * CT], wv);
#pragma unroll
            for (int i = 0; i < 4; i++)
#pragma unroll
                for (int c = 0; c < CT; c++) acc[i][c] = fmaf(av[i], wv[c], acc[i][c]);
        }
    }

    // ---------------- epilogue ----------------
    float bb[CT], cc[CT];
#pragma unroll
    for (int c = 0; c < CT; c++) {
        bb[c] = bias[tc * CT + c];
        cc[c] = HASCB ? cbv[tc * CT + c] : 0.f;
    }
    float ps[CT], pq[CT];
#pragma unroll
    for (int c = 0; c < CT; c++) { ps[c] = 0.f; pq[c] = 0.f; }

#pragma unroll
    for (int i = 0; i < 4; i++) {
        int local = tr * 4 + i;
        int r = row0 + local;
        if (r < n) {
            float vs = HASCB ? vsL[local] : 0.f;
            float* o = Hout + (size_t)r * C + tc * CT;
#pragma unroll
            for (int c = 0; c < CT; c++) {
                float v = acc[i][c] + vs * cc[c] + bb[c];
                v = fmaxf(v, 0.f);
                o[c] = v;
                if (DOBN) { ps[c] += v; pq[c] += v * v; }
            }
        }
    }
    if (DOBN) {
#pragma unroll
        for (int c = 0; c < CT; c++) {
            ps[c] += __shfl_xor(ps[c], 16);
            ps[c] += __shfl_xor(ps[c], 32);
            pq[c] += __shfl_xor(pq[c], 16);
            pq[c] += __shfl_xor(pq[c], 32);
        }
        if ((t & 48) == 0) {
#pragma unroll
            for (int c = 0; c < CT; c++) {
                atomicAdd(&redS[tc * CT + c], ps[c]);
                atomicAdd(&redQ[tc * CT + c], pq[c]);
            }
        }
        __syncthreads();
        if (t < C) {
            atomicAdd(&bsum[t], redS[t]);
            atomicAdd(&bsumsq[t], redQ[t]);
        }
    }
}

// ============================ Tiled GEMM (MLP): 64-row tile, chunked W ============================
template <int K, int C, bool DOBN, bool HASCB>
__global__ __launch_bounds__(256)
void gemmF(const float* __restrict__ A1, int ld1, int split,
           const float* __restrict__ A2, int ld2,
           const float* __restrict__ W, const float* __restrict__ bias,
           const float* __restrict__ cbv, const float* __restrict__ vsum,
           float* __restrict__ Out, float* __restrict__ bsum,
           float* __restrict__ bsumsq, int n) {
    constexpr int CT = C / 16;
    __shared__ float Wc[16 * C];
    __shared__ float At[16][68];

    int t  = threadIdx.x;
    int tc = t & 15, tr = t >> 4;
    int row0 = blockIdx.x * 64;

    int srow = t >> 2;
    int gr = row0 + srow; if (gr >= n) gr = n - 1;
    int kh = (t & 3) * 4;

    float acc[4][CT];
#pragma unroll
    for (int i = 0; i < 4; i++)
#pragma unroll
        for (int c = 0; c < CT; c++) acc[i][c] = 0.f;

#pragma unroll 1
    for (int kb = 0; kb < K; kb += 16) {
        __syncthreads();
        for (int i = t * 4; i < 16 * C; i += 1024)
            *(f4a*)&Wc[i] = *(const f4u*)&W[(size_t)kb * C + i];
        {
            int kg = kb + kh;
            const float* src = (kg < split) ? (A1 + (size_t)gr * ld1 + kg)
                                            : (A2 + (size_t)gr * ld2 + (kg - split));
            f4u v = *(const f4u*)src;
#pragma unroll
            for (int e = 0; e < 4; e++) At[kh + e][srow] = v[e];
        }
        __syncthreads();
#pragma unroll
        for (int kk = 0; kk < 16; kk++) {
            f4a av = *(const f4a*)&At[kk][tr * 4];
            float wv[CT];
            ldw<CT>(&Wc[kk * C + tc * CT], wv);
#pragma unroll
            for (int i = 0; i < 4; i++)
#pragma unroll
                for (int c = 0; c < CT; c++) acc[i][c] = fmaf(av[i], wv[c], acc[i][c]);
        }
    }

    float bb[CT], cc[CT];
#pragma unroll
    for (int c = 0; c < CT; c++) {
        bb[c] = bias[tc * CT + c];
        cc[c] = HASCB ? cbv[tc * CT + c] : 0.f;
    }

#pragma unroll
    for (int i = 0; i < 4; i++) {
        int r = row0 + tr * 4 + i;
        if (r < n) {
            float vs = HASCB ? vsum[r] : 0.f;
            float* o = Out + (size_t)r * C + tc * CT;
#pragma unroll
            for (int c = 0; c < CT; c++) {
                float v = acc[i][c] + vs * cc[c] + bb[c];
                v = fmaxf(v, 0.f);
                o[c] = v;
            }
        }
    }
}

// ============================ BN fold ============================
template <int C>
__global__ __launch_bounds__(256)
void fold_kernel(const float* __restrict__ W, float* __restrict__ bsum,
                 float* __restrict__ bsumsq, float* __restrict__ Wf,
                 float* __restrict__ cb, int N) {
    __shared__ float mean[96], inv[96];
    int t = threadIdx.x;
    float rn = 1.0f / (float)N;
    if (t < 96) {
        float mu  = bsum[t] * rn;
        float var = bsumsq[t] * rn - mu * mu;
        mean[t] = mu;
        inv[t]  = rsqrtf(var + 1e-5f);
        bsum[t] = 0.f;
        bsumsq[t] = 0.f;
    }
    __syncthreads();
    for (int i = t; i < 96 * C; i += 256) {
        int k = i / C;
        Wf[i] = inv[k] * W[i];
    }
    if (t < C) {
        float s = 0.f;
        for (int k = 0; k < 96; k++) s += mean[k] * inv[k] * W[k * C + t];
        cb[t] = -s;
    }
}

// ============================ final dot (64->1) + global min ============================
__global__ __launch_bounds__(256)
void dot_min_kernel(const float* __restrict__ A, const float* __restrict__ M3w,
                    const float* __restrict__ M3b, float* __restrict__ m,
                    unsigned* __restrict__ gmin, int n) {
    int lane = threadIdx.x & 63;
    int wv   = threadIdx.x >> 6;
    float w  = M3w[lane];
    float b  = M3b[0];
    float lmin = 3.4e38f;
    int nw = gridDim.x * 4;
    for (int r = blockIdx.x * 4 + wv; r < n; r += nw) {
        float v = A[(size_t)r * 64 + lane] * w;
#pragma unroll
        for (int o = 32; o; o >>= 1) v += __shfl_down(v, o);
        if (lane == 0) {
            float mv = v + b;
            m[r] = mv;
            lmin = fminf(lmin, mv);
        }
    }
#pragma unroll
    for (int o = 32; o; o >>= 1) lmin = fminf(lmin, __shfl_down(lmin, o));
    __shared__ float sm[4];
    if (lane == 0) sm[wv] = lmin;
    __syncthreads();
    if (threadIdx.x == 0) {
        float mn = fminf(fminf(sm[0], sm[1]), fminf(sm[2], sm[3]));
        unsigned u = __float_as_uint(mn);
        unsigned key = (u >> 31) ? ~u : (u | 0x80000000u);
        atomicMin(gmin, key);
    }
}

__global__ void where_kernel(const float* __restrict__ x, float* __restrict__ m,
                             const unsigned* __restrict__ gmin, int n) {
    int i = blockIdx.x * blockDim.x + threadIdx.x;
    if (i < n) {
        unsigned k = *gmin;
        unsigned u = (k >> 31) ? (k ^ 0x80000000u) : ~k;
        float g = __uint_as_float(u);
        if (x[(size_t)i * XLD + 160] == 0.0f) m[i] = g;
    }
}

// ============================ exact radix select ============================
__device__ inline unsigned fkey(float f) {
    unsigned u = __float_as_uint(f);
    return (u >> 31) ? ~u : (u | 0x80000000u);
}

__global__ __launch_bounds__(1024)
void select_kernel(const float* __restrict__ m, int n, int kwant, float* __restrict__ thresh) {
    __shared__ unsigned hist[256];
    __shared__ unsigned sprefix;
    __shared__ int skk;
    int t = threadIdx.x;
    if (t == 0) { sprefix = 0u; skk = kwant; }
    for (int pass = 0; pass < 4; ++pass) {
        if (t < 256) hist[t] = 0u;
        __syncthreads();
        int shift = 24 - 8 * pass;
        unsigned pfx = sprefix;
        for (int i = t; i < n; i += 1024) {
            unsigned key = fkey(m[i]);
            bool ok = (pass == 0) || ((key >> (shift + 8)) == (pfx >> (shift + 8)));
            if (ok) atomicAdd(&hist[(key >> shift) & 255u], 1u);
        }
        __syncthreads();
        if (t == 0) {
            int cum = 0, kk = skk, chosen = 0;
            for (int b = 255; b >= 0; b--) {
                cum += (int)hist[b];
                if (cum >= kk) { chosen = b; kk -= (cum - (int)hist[b]); break; }
            }
            sprefix = pfx | ((unsigned)chosen << shift);
            skk = kk;
        }
        __syncthreads();
    }
    if (t == 0) {
        unsigned key = sprefix;
        unsigned u = (key >> 31) ? (key ^ 0x80000000u) : ~key;
        *thresh = __uint_as_float(u);
    }
}

__global__ void mask_kernel(const float* __restrict__ m, const float* __restrict__ thresh,
                            float* __restrict__ out, int n) {
    int i = blockIdx.x * blockDim.x + threadIdx.x;
    if (i < n) {
        float t = *thresh, v = m[i];
        out[i] = (v > t) ? v * (1.0f / v) : 0.0f;
    }
}

// ============================ launch ============================
extern "C" void kernel_launch(void* const* d_in, const int* in_sizes, int n_in,
                              void* d_out, int out_size, void* d_ws, size_t ws_size,
                              hipStream_t stream) {
    const float* x   = (const float*)d_in[0];
    const int*   row = (const int*)d_in[1];
    const int*   col = (const int*)d_in[2];
    const float* val = (const float*)d_in[3];
    const float* W1  = (const float*)d_in[4];
    const float* b1  = (const float*)d_in[5];
    const float* W2  = (const float*)d_in[6];
    const float* b2  = (const float*)d_in[7];
    const float* W3  = (const float*)d_in[8];
    const float* b3  = (const float*)d_in[9];
    const float* W4  = (const float*)d_in[10];
    const float* b4  = (const float*)d_in[11];
    const float* W5  = (const float*)d_in[12];
    const float* b5  = (const float*)d_in[13];
    const float* M1w = (const float*)d_in[14];
    const float* M1b = (const float*)d_in[15];
    const float* M2w = (const float*)d_in[16];
    const float* M2b = (const float*)d_in[17];
    const float* M3w = (const float*)d_in[18];
    const float* M3b = (const float*)d_in[19];

    const int n = in_sizes[0] / XLD;   // 50000
    const int E = in_sizes[1];         // 800000

    char* ws = (char*)d_ws;
    size_t off = 0;
    auto carve = [&](size_t bytes) -> void* {
        void* p = ws + off;
        off = (off + bytes + 255) & ~(size_t)255;
        return p;
    };
    int*      offs   = (int*)carve((size_t)(n + 1) * 4);
    int*      cursor = (int*)carve((size_t)n * 4);
    int*      bsums  = (int*)carve(256 * 4);
    int2*     edges  = (int2*)carve((size_t)E * 8);
    float*    h      = (float*)carve((size_t)n * 96 * 4);   // ping
    float*    big    = (float*)carve((size_t)n * 128 * 4);  // pong / MLP a1
    float*    Wf     = (float*)carve(96 * 96 * 4);
    float*    stats  = (float*)carve(192 * 4);
    float*    cb     = (float*)carve(96 * 4);
    float*    m      = (float*)carve((size_t)n * 4);
    unsigned* gmin   = (unsigned*)carve(4);
    float*    thresh = (float*)carve(4);
    float* bsum   = stats;
    float* bsumsq = stats + 96;

    hipMemsetAsync(cursor, 0, (size_t)n * 4, stream);
    hipMemsetAsync(stats, 0, 192 * 4, stream);
    hipMemsetAsync(gmin, 0xFF, 4, stream);

    // CSR build
    const int nb = (n + 255) / 256;
    hist_kernel<<<512, 256, 0, stream>>>(row, cursor, E);
    scan1_kernel<<<nb, 256, 0, stream>>>(cursor, offs, bsums, n);
    scan2_kernel<<<1, 256, 0, stream>>>(bsums, nb);
    scan3_kernel<<<nb, 256, 0, stream>>>(offs, cursor, bsums, n, E);
    scatter_kernel<<<512, 256, 0, stream>>>(row, col, val, cursor, edges, E);

    const int gF = (n + 63) / 64;       // 782 fused/gemm tiles

    // Layer 1: gather x[:, :128] -> h1 = relu(agg@W1 + b1), BN stats
    fusedL<4, 96, true, false><<<gF, 256, 0, stream>>>(x, XLD, offs, edges,
        W1, b1, nullptr, h, bsum, bsumsq, n);

    // Layer 2: h -> big
    fold_kernel<96><<<1, 256, 0, stream>>>(W2, bsum, bsumsq, Wf, cb, n);
    fusedL<3, 96, true, true><<<gF, 256, 0, stream>>>(h, 96, offs, edges,
        Wf, b2, cb, big, bsum, bsumsq, n);

    // Layer 3: big -> h
    fold_kernel<96><<<1, 256, 0, stream>>>(W3, bsum, bsumsq, Wf, cb, n);
    fusedL<3, 96, true, true><<<gF, 256, 0, stream>>>(big, 96, offs, edges,
        Wf, b3, cb, h, bsum, bsumsq, n);

    // Layer 4: h -> big
    fold_kernel<96><<<1, 256, 0, stream>>>(W4, bsum, bsumsq, Wf, cb, n);
    fusedL<3, 96, true, true><<<gF, 256, 0, stream>>>(h, 96, offs, edges,
        Wf, b4, cb, big, bsum, bsumsq, n);

    // Layer 5: big -> h (n x 64), no BN stats
    fold_kernel<64><<<1, 256, 0, stream>>>(W5, bsum, bsumsq, Wf, cb, n);
    fusedL<3, 64, false, true><<<gF, 256, 0, stream>>>(big, 96, offs, edges,
        Wf, b5, cb, h, bsum, bsumsq, n);

    // MLP: a1 = relu([h5 | x[:,128:160]] @ M1w + M1b) -> big (n x 128)
    gemmF<96, 128, false, false><<<gF, 256, 0, stream>>>(h, 64, 64, x + 128, XLD,
        M1w, M1b, nullptr, nullptr, big, bsum, bsumsq, n);
    // a2 = relu(a1 @ M2w + M2b) -> h (n x 64)
    gemmF<128, 64, false, false><<<gF, 256, 0, stream>>>(big, 128, 128, big, 128,
        M2w, M2b, nullptr, nullptr, h, bsum, bsumsq, n);

    // m = a2 @ M3w + M3b ; global min
    dot_min_kernel<<<256, 256, 0, stream>>>(h, M3w, M3b, m, gmin, n);

    // where(grp==0, min, m)
    where_kernel<<<(n + 255) / 256, 256, 0, stream>>>(x, m, gmin, n);

    // exact 71st-largest threshold
    select_kernel<<<1, 1024, 0, stream>>>(m, n, 71, thresh);

    // out = m>thresh ? m*(1/m) : 0
    mask_kernel<<<(n + 255) / 256, 256, 0, stream>>>(m, thresh, (float*)d_out, n);
}